// Round 19
// baseline (171.643 us; speedup 1.0000x reference)
//
#include <hip/hip_runtime.h>
#include <hip/hip_bf16.h>
#include <math.h>

#define NNODES 50000
#define NEDGES 800000
#define IN1 512
#define IN2 256
#define NOUT 128
#define FTOT 256   // combined feature width (two GCN branches)

typedef __attribute__((ext_vector_type(4))) short short4v;
typedef __attribute__((ext_vector_type(8))) short frag_ab;
typedef __attribute__((ext_vector_type(4))) float frag_cd;

// ---------------- workspace layout (bytes) ----------------
#define OFF_XW      ((size_t)0)           // N*256 bf16 = 25,600,000
#define OFF_W1T     ((size_t)25600000)    // 128x512 bf16 [col][k]
#define OFF_W2T     ((size_t)25731072)    // 128x256 bf16 [col][k]
#define OFF_DEG     ((size_t)25796608)    // N int
#define OFF_DINV    ((size_t)25996672)    // N f32
#define OFF_ROWPTR  ((size_t)26196736)    // (N+1) int
#define OFF_BSUM    ((size_t)26596864)    // 256 int
#define OFF_ADJ     ((size_t)26600960)    // E int
#define OFF_RANK    ((size_t)29800960)    // E int (edge rank within dst, from hist)

__device__ __forceinline__ short f2bf(float f) {
    union { float f; unsigned u; } x; x.f = f;
    unsigned r = x.u + 0x7fffu + ((x.u >> 16) & 1u);   // RNE
    return (short)(r >> 16);
}
__device__ __forceinline__ float bf2f(unsigned short u) {
    union { unsigned u; float f; } x; x.u = ((unsigned)u) << 16;
    return x.f;
}

// ---- inline-asm vmem primitives (R17-proven pattern: issue batch, counted
// ladder, consume in the SAME scope -- no in-flight registers cross barriers
// or scheduling regions, which is what NaN'd R18). sched_barrier after each
// wait per rule #18.
__device__ __forceinline__ float4 gload(const float* p) {
    float4 r;
    asm volatile("global_load_dwordx4 %0, %1, off" : "=v"(r) : "v"(p));
    return r;
}
__device__ __forceinline__ frag_ab gloadb(const short* p) {
    frag_ab r;
    asm volatile("global_load_dwordx4 %0, %1, off" : "=v"(r) : "v"(p));
    return r;
}
template<int N> __device__ __forceinline__ void vwait() {
    if constexpr (N == 0)      asm volatile("s_waitcnt vmcnt(0)" ::: "memory");
    else if constexpr (N == 2) asm volatile("s_waitcnt vmcnt(2)" ::: "memory");
    else                       asm volatile("s_waitcnt vmcnt(4)" ::: "memory");
    __builtin_amdgcn_sched_barrier(0);
}

// ---------------- D0: W transpose + f32->bf16 ----------------
__global__ __launch_bounds__(256) void wcvt_kernel(const float* __restrict__ W1, const float* __restrict__ W2,
                                                   short* __restrict__ w1t, short* __restrict__ w2t) {
    int t = blockIdx.x * 256 + threadIdx.x;
    if (t < IN1 * NOUT) {
        int c = t & 127, k = t >> 7;
        w1t[c * IN1 + k] = f2bf(W1[t]);
    } else if (t < (IN1 + IN2) * NOUT) {
        int u = t - IN1 * NOUT;
        int c = u & 127, k = u >> 7;
        w2t[c * IN2 + k] = f2bf(W2[u]);
    }
}

// ---------------- GEMM: barrier-free streaming + asm counted ladder ----------
// One wave = 32 rows x 128 cols (R11's best merged structure). Per K-step:
// issue 8 B-frag loads (L2-hot W) + 4 A loads via asm (explicit dest regs ->
// compiler cannot sink/serialize; R13 measured the compiler-collapsed chain
// at ~7100cy/step), then counted ladder: vmcnt(2) -> B + row0-A ready -> 8
// MFMA; vmcnt(0) -> row1-A -> 8 MFMA. ZERO barriers, ZERO LDS: the issue-to-
// use latency is covered by wave-level TLP (~4/SIMD), the gather's regime.
template<int K, int COLOFF>
__device__ __forceinline__ void gemm_rows32_asm(const float* __restrict__ X, const short* __restrict__ Wt,
                                                short* __restrict__ xw, int tile, int n) {
    constexpr int NSTEP = K / 32;    // 16 (mod1), 8 (mod2)
    const int lane = threadIdx.x & 63;
    const int l15 = lane & 15, kof = lane >> 4;
    const int r0 = tile * 32;
    int row0 = r0 + l15;      if (row0 >= n) row0 = n - 1;
    int row1 = r0 + 16 + l15; if (row1 >= n) row1 = n - 1;
    const float* a0p = X + (size_t)row0 * K + kof * 8;
    const float* a1p = X + (size_t)row1 * K + kof * 8;
    const short* bp  = Wt + (size_t)l15 * K + kof * 8;

    frag_cd acc0[8], acc1[8];
    #pragma unroll
    for (int cf = 0; cf < 8; ++cf) {
        acc0[cf] = (frag_cd){0.f, 0.f, 0.f, 0.f};
        acc1[cf] = (frag_cd){0.f, 0.f, 0.f, 0.f};
    }

    auto cvt = [&](float4 m0, float4 m1) -> frag_ab {
        frag_ab o;
        o[0] = f2bf(m0.x); o[1] = f2bf(m0.y); o[2] = f2bf(m0.z); o[3] = f2bf(m0.w);
        o[4] = f2bf(m1.x); o[5] = f2bf(m1.y); o[6] = f2bf(m1.z); o[7] = f2bf(m1.w);
        return o;
    };

    #pragma unroll
    for (int s = 0; s < NSTEP; ++s) {
        // issue order (FIFO): b0..b7, a00, a01, a10, a11  -> 12 outstanding
        frag_ab b0 = gloadb(bp + (size_t)0 * 16 * K + s * 32);
        frag_ab b1 = gloadb(bp + (size_t)1 * 16 * K + s * 32);
        frag_ab b2 = gloadb(bp + (size_t)2 * 16 * K + s * 32);
        frag_ab b3 = gloadb(bp + (size_t)3 * 16 * K + s * 32);
        frag_ab b4 = gloadb(bp + (size_t)4 * 16 * K + s * 32);
        frag_ab b5 = gloadb(bp + (size_t)5 * 16 * K + s * 32);
        frag_ab b6 = gloadb(bp + (size_t)6 * 16 * K + s * 32);
        frag_ab b7 = gloadb(bp + (size_t)7 * 16 * K + s * 32);
        float4 a00 = gload(a0p + s * 32), a01 = gload(a0p + s * 32 + 4);
        float4 a10 = gload(a1p + s * 32), a11 = gload(a1p + s * 32 + 4);

        vwait<2>();                       // b0..b7, a00, a01 retired
        frag_ab fa0 = cvt(a00, a01);
        __builtin_amdgcn_s_setprio(1);
        acc0[0] = __builtin_amdgcn_mfma_f32_16x16x32_bf16(b0, fa0, acc0[0], 0, 0, 0);
        acc0[1] = __builtin_amdgcn_mfma_f32_16x16x32_bf16(b1, fa0, acc0[1], 0, 0, 0);
        acc0[2] = __builtin_amdgcn_mfma_f32_16x16x32_bf16(b2, fa0, acc0[2], 0, 0, 0);
        acc0[3] = __builtin_amdgcn_mfma_f32_16x16x32_bf16(b3, fa0, acc0[3], 0, 0, 0);
        acc0[4] = __builtin_amdgcn_mfma_f32_16x16x32_bf16(b4, fa0, acc0[4], 0, 0, 0);
        acc0[5] = __builtin_amdgcn_mfma_f32_16x16x32_bf16(b5, fa0, acc0[5], 0, 0, 0);
        acc0[6] = __builtin_amdgcn_mfma_f32_16x16x32_bf16(b6, fa0, acc0[6], 0, 0, 0);
        acc0[7] = __builtin_amdgcn_mfma_f32_16x16x32_bf16(b7, fa0, acc0[7], 0, 0, 0);
        __builtin_amdgcn_s_setprio(0);

        vwait<0>();                       // a10, a11 retired
        frag_ab fa1 = cvt(a10, a11);
        __builtin_amdgcn_s_setprio(1);
        acc1[0] = __builtin_amdgcn_mfma_f32_16x16x32_bf16(b0, fa1, acc1[0], 0, 0, 0);
        acc1[1] = __builtin_amdgcn_mfma_f32_16x16x32_bf16(b1, fa1, acc1[1], 0, 0, 0);
        acc1[2] = __builtin_amdgcn_mfma_f32_16x16x32_bf16(b2, fa1, acc1[2], 0, 0, 0);
        acc1[3] = __builtin_amdgcn_mfma_f32_16x16x32_bf16(b3, fa1, acc1[3], 0, 0, 0);
        acc1[4] = __builtin_amdgcn_mfma_f32_16x16x32_bf16(b4, fa1, acc1[4], 0, 0, 0);
        acc1[5] = __builtin_amdgcn_mfma_f32_16x16x32_bf16(b5, fa1, acc1[5], 0, 0, 0);
        acc1[6] = __builtin_amdgcn_mfma_f32_16x16x32_bf16(b6, fa1, acc1[6], 0, 0, 0);
        acc1[7] = __builtin_amdgcn_mfma_f32_16x16x32_bf16(b7, fa1, acc1[7], 0, 0, 0);
        __builtin_amdgcn_s_setprio(0);
    }

    // epilogue: lane holds rows {row0,row1}, cols kof*4 + cf*16 (+0..3)
    if (r0 + l15 < n) {
        short* dst = xw + (size_t)row0 * FTOT + COLOFF + kof * 4;
        #pragma unroll
        for (int cf = 0; cf < 8; ++cf) {
            short4v pk;
            pk[0] = f2bf(acc0[cf][0]); pk[1] = f2bf(acc0[cf][1]);
            pk[2] = f2bf(acc0[cf][2]); pk[3] = f2bf(acc0[cf][3]);
            *reinterpret_cast<short4v*>(dst + cf * 16) = pk;
        }
    }
    if (r0 + 16 + l15 < n) {
        short* dst = xw + (size_t)row1 * FTOT + COLOFF + kof * 4;
        #pragma unroll
        for (int cf = 0; cf < 8; ++cf) {
            short4v pk;
            pk[0] = f2bf(acc1[cf][0]); pk[1] = f2bf(acc1[cf][1]);
            pk[2] = f2bf(acc1[cf][2]); pk[3] = f2bf(acc1[cf][3]);
            *reinterpret_cast<short4v*>(dst + cf * 16) = pk;
        }
    }
}

// ONE dispatch: gemm1 || gemm2 || hist(+rank). No barriers anywhere -> mixed
// wave roles safe. LPT: K=512 waves first. Strict tail guards (R8 lesson).
__global__ __launch_bounds__(256, 2) void gall_kernel(const float* __restrict__ x1, const short* __restrict__ w1t,
                                                      const float* __restrict__ x2, const short* __restrict__ w2t,
                                                      short* __restrict__ xw, const int* __restrict__ ei,
                                                      int* __restrict__ deg, int* __restrict__ rank,
                                                      int n, int e, int t1w, int t2w, int nhw) {
    int w = blockIdx.x * 4 + (threadIdx.x >> 6);
    if (w < t1w) {
        gemm_rows32_asm<IN1, 0>(x1, w1t, xw, w, n);
    } else if (w < t1w + t2w) {
        gemm_rows32_asm<IN2, 128>(x2, w2t, xw, w - t1w, n);
    } else if (w < t1w + t2w + nhw) {
        int lane = threadIdx.x & 63;
        for (int i = (w - t1w - t2w) * 64 + lane; i < e; i += nhw * 64) {
            int old = atomicAdd(&deg[ei[e + i]], 1);
            rank[i] = old;
        }
    }
}

// ---------------- scans (proven trio) ----------------
__global__ __launch_bounds__(256) void scan_part_kernel(const int* __restrict__ deg, float* __restrict__ dinv,
                                                        int* __restrict__ bsum, int n) {
    __shared__ int s[256];
    int t = threadIdx.x;
    int i = blockIdx.x * 256 + t;
    int v = (i < n) ? deg[i] : 0;
    if (i < n) dinv[i] = rsqrtf((float)(v + 1));
    s[t] = v; __syncthreads();
    #pragma unroll
    for (int off = 128; off > 0; off >>= 1) {
        if (t < off) s[t] += s[t + off];
        __syncthreads();
    }
    if (t == 0) bsum[blockIdx.x] = s[0];
}

__global__ __launch_bounds__(256) void scan_top_kernel(int* __restrict__ bsum, int nb) {
    __shared__ int s[256];
    int t = threadIdx.x;
    int v = (t < nb) ? bsum[t] : 0;
    s[t] = v; __syncthreads();
    for (int off = 1; off < 256; off <<= 1) {
        int u = (t >= off) ? s[t - off] : 0;
        __syncthreads();
        s[t] += u;
        __syncthreads();
    }
    if (t < nb) bsum[t] = s[t] - v;
}

__global__ __launch_bounds__(256) void scan_write_kernel(const int* __restrict__ deg, const int* __restrict__ bsum,
                                                         int* __restrict__ rowptr, int n) {
    __shared__ int s[256];
    int t = threadIdx.x;
    int i = blockIdx.x * 256 + t;
    int v = (i < n) ? deg[i] : 0;
    s[t] = v; __syncthreads();
    for (int off = 1; off < 256; off <<= 1) {
        int u = (t >= off) ? s[t - off] : 0;
        __syncthreads();
        s[t] += u;
        __syncthreads();
    }
    int base = bsum[blockIdx.x];
    if (i < n) rowptr[i] = base + s[t] - v;
    if (i == n - 1) rowptr[n] = base + s[t];
}

// ---------------- D3: rank-based CSR fill (atomic-free) ----------------
__global__ __launch_bounds__(256) void fill_rank_kernel(const int* __restrict__ ei, const int* __restrict__ rowptr,
                                                        const int* __restrict__ rank, int* __restrict__ adj, int e) {
    int i = blockIdx.x * 256 + threadIdx.x;
    if (i < e) {
        int dst = ei[e + i];
        adj[rowptr[dst] + rank[i]] = ei[i];
    }
}

// ---------------- D4: gather + epilogue (unchanged) ----------------
__global__ __launch_bounds__(256) void gather_kernel(const unsigned short* __restrict__ xw,
                                                     const int* __restrict__ rowptr,
                                                     const int* __restrict__ adj,
                                                     const float* __restrict__ dinv,
                                                     const float* __restrict__ b1,
                                                     const float* __restrict__ b2,
                                                     float* __restrict__ out, int n) {
    int wid  = (int)((blockIdx.x * (size_t)blockDim.x + threadIdx.x) >> 6);
    int lane = threadIdx.x & 63;
    if (wid >= n) return;

    const ushort4* base = reinterpret_cast<const ushort4*>(xw);
    float ax = 0.f, ay = 0.f, az = 0.f, aw = 0.f;

    const int s = rowptr[wid], e = rowptr[wid + 1];
    int i = s;
    for (; i + 3 < e; i += 4) {
        int s0 = adj[i], s1 = adj[i + 1], s2 = adj[i + 2], s3 = adj[i + 3];
        float w0 = dinv[s0], w1 = dinv[s1], w2 = dinv[s2], w3 = dinv[s3];
        ushort4 v0 = base[(size_t)s0 * 64 + lane];
        ushort4 v1 = base[(size_t)s1 * 64 + lane];
        ushort4 v2 = base[(size_t)s2 * 64 + lane];
        ushort4 v3 = base[(size_t)s3 * 64 + lane];
        ax = fmaf(bf2f(v0.x), w0, fmaf(bf2f(v1.x), w1, fmaf(bf2f(v2.x), w2, fmaf(bf2f(v3.x), w3, ax))));
        ay = fmaf(bf2f(v0.y), w0, fmaf(bf2f(v1.y), w1, fmaf(bf2f(v2.y), w2, fmaf(bf2f(v3.y), w3, ay))));
        az = fmaf(bf2f(v0.z), w0, fmaf(bf2f(v1.z), w1, fmaf(bf2f(v2.z), w2, fmaf(bf2f(v3.z), w3, az))));
        aw = fmaf(bf2f(v0.w), w0, fmaf(bf2f(v1.w), w1, fmaf(bf2f(v2.w), w2, fmaf(bf2f(v3.w), w3, aw))));
    }
    for (; i < e; ++i) {
        int s0 = adj[i];
        float w0 = dinv[s0];
        ushort4 v0 = base[(size_t)s0 * 64 + lane];
        ax = fmaf(bf2f(v0.x), w0, ax); ay = fmaf(bf2f(v0.y), w0, ay);
        az = fmaf(bf2f(v0.z), w0, az); aw = fmaf(bf2f(v0.w), w0, aw);
    }
    float di = dinv[wid];
    {   // self-loop
        ushort4 v = base[(size_t)wid * 64 + lane];
        ax = fmaf(bf2f(v.x), di, ax); ay = fmaf(bf2f(v.y), di, ay);
        az = fmaf(bf2f(v.z), di, az); aw = fmaf(bf2f(v.w), di, aw);
    }
    float4 bias = (lane < 32) ? reinterpret_cast<const float4*>(b1)[lane]
                              : reinterpret_cast<const float4*>(b2)[lane - 32];
    float4 v;
    v.x = fmaxf(fmaf(ax, di, bias.x), 0.f);
    v.y = fmaxf(fmaf(ay, di, bias.y), 0.f);
    v.z = fmaxf(fmaf(az, di, bias.z), 0.f);
    v.w = fmaxf(fmaf(aw, di, bias.w), 0.f);

    float4 h;
    h.x = v.x + __shfl_xor(v.x, 32);
    h.y = v.y + __shfl_xor(v.y, 32);
    h.z = v.z + __shfl_xor(v.z, 32);
    h.w = v.w + __shfl_xor(v.w, 32);

    float m = fmaxf(fmaxf(h.x, h.y), fmaxf(h.z, h.w));
    #pragma unroll
    for (int off = 1; off <= 16; off <<= 1) m = fmaxf(m, __shfl_xor(m, off));
    float ssum = __expf(h.x - m) + __expf(h.y - m) + __expf(h.z - m) + __expf(h.w - m);
    #pragma unroll
    for (int off = 1; off <= 16; off <<= 1) ssum += __shfl_xor(ssum, off);
    float lse = m + __logf(ssum);

    if (lane < 32) {
        float4 y;
        y.x = h.x - lse; y.y = h.y - lse; y.z = h.z - lse; y.w = h.w - lse;
        reinterpret_cast<float4*>(out)[(size_t)wid * 32 + lane] = y;
    }
}

// ---------------- launcher ----------------
extern "C" void kernel_launch(void* const* d_in, const int* in_sizes, int n_in,
                              void* d_out, int out_size, void* d_ws, size_t ws_size,
                              hipStream_t stream) {
    const float* x1 = (const float*)d_in[0];
    const float* x2 = (const float*)d_in[1];
    const int*   ei = (const int*)d_in[2];
    const float* W1 = (const float*)d_in[3];
    const float* b1 = (const float*)d_in[4];
    const float* W2 = (const float*)d_in[5];
    const float* b2 = (const float*)d_in[6];
    float* out = (float*)d_out;

    const int n = in_sizes[0] / IN1;       // 50000
    const int e = in_sizes[2] / 2;         // 800000

    char* ws = (char*)d_ws;
    short* xw     = (short*)(ws + OFF_XW);
    short* w1t    = (short*)(ws + OFF_W1T);
    short* w2t    = (short*)(ws + OFF_W2T);
    int*   deg    = (int*)  (ws + OFF_DEG);
    float* dinv   = (float*)(ws + OFF_DINV);
    int*   rowptr = (int*)  (ws + OFF_ROWPTR);
    int*   bsum   = (int*)  (ws + OFF_BSUM);
    int*   adj    = (int*)  (ws + OFF_ADJ);
    int*   rank   = (int*)  (ws + OFF_RANK);

    const int nb_n = (n + 255) / 256;      // 196
    const int nb_e = (e + 255) / 256;      // 3125
    const int nwb  = ((IN1 + IN2) * NOUT + 255) / 256;   // 384
    const int t1w  = (n + 31) / 32;        // 1563 gemm waves (mod1, K=512: LPT first)
    const int t2w  = t1w;                  // 1563 gemm waves (mod2)
    const int nhw  = 1024;                 // hist waves (grid-stride)

    // D0: zero deg + W convert
    hipMemsetAsync(deg, 0, (size_t)n * sizeof(int), stream);
    wcvt_kernel<<<nwb, 256, 0, stream>>>(W1, W2, w1t, w2t);
    // D1: gemm1 || gemm2 || hist(+rank) -- one dispatch, no barriers
    const int totw = t1w + t2w + nhw;      // 4150 waves
    gall_kernel<<<(totw + 3) / 4, 256, 0, stream>>>(x1, w1t, x2, w2t, xw, ei, deg, rank, n, e, t1w, t2w, nhw);
    // D2: scans -> dinv, rowptr
    scan_part_kernel<<<nb_n, 256, 0, stream>>>(deg, dinv, bsum, n);
    scan_top_kernel<<<1, 256, 0, stream>>>(bsum, nb_n);
    scan_write_kernel<<<nb_n, 256, 0, stream>>>(deg, bsum, rowptr, n);
    // D3: rank-based CSR fill (atomic-free)
    fill_rank_kernel<<<nb_e, 256, 0, stream>>>(ei, rowptr, rank, adj, e);
    // D4: gather + relu + add + log_softmax
    const int gb = (n + 3) / 4;
    gather_kernel<<<gb, 256, 0, stream>>>((const unsigned short*)xw, rowptr, adj, dinv, b1, b2, out, n);
}

// Round 20
// 171.190 us; speedup vs baseline: 1.0026x; 1.0026x over previous
//
#include <hip/hip_runtime.h>
#include <hip/hip_bf16.h>
#include <math.h>

#define NNODES 50000
#define NEDGES 800000
#define IN1 512
#define IN2 256
#define NOUT 128
#define FTOT 256   // combined feature width (two GCN branches)

typedef __attribute__((ext_vector_type(4))) short short4v;
typedef __attribute__((ext_vector_type(8))) short frag_ab;
typedef __attribute__((ext_vector_type(4))) float frag_cd;

// ---------------- workspace layout (bytes) ----------------
#define OFF_XW      ((size_t)0)           // N*256 bf16 = 25,600,000
#define OFF_W1T     ((size_t)25600000)    // 128x512 bf16 [col][k]
#define OFF_W2T     ((size_t)25731072)    // 128x256 bf16 [col][k]
#define OFF_DEG     ((size_t)25796608)    // N int
#define OFF_DINV    ((size_t)25996672)    // N f32
#define OFF_ROWPTR  ((size_t)26196736)    // (N+1) int
#define OFF_BSUM    ((size_t)26596864)    // 256 int (unused this round)
#define OFF_ADJ     ((size_t)26600960)    // E int
#define OFF_RANK    ((size_t)29800960)    // E int (edge rank within dst, from hist)

__device__ __forceinline__ short f2bf(float f) {
    union { float f; unsigned u; } x; x.f = f;
    unsigned r = x.u + 0x7fffu + ((x.u >> 16) & 1u);   // RNE
    return (short)(r >> 16);
}
__device__ __forceinline__ float bf2f(unsigned short u) {
    union { unsigned u; float f; } x; x.u = ((unsigned)u) << 16;
    return x.f;
}

// ---- inline-asm vmem primitives (R17-proven: issue batch + counted ladder +
// consume in the SAME scope; no in-flight registers cross barriers (R18 NaN).
// sched_barrier after each wait per rule #18.
__device__ __forceinline__ float4 gload(const float* p) {
    float4 r;
    asm volatile("global_load_dwordx4 %0, %1, off" : "=v"(r) : "v"(p));
    return r;
}
__device__ __forceinline__ frag_ab gloadb(const short* p) {
    frag_ab r;
    asm volatile("global_load_dwordx4 %0, %1, off" : "=v"(r) : "v"(p));
    return r;
}
template<int N> __device__ __forceinline__ void vwait() {
    if constexpr (N == 0)      asm volatile("s_waitcnt vmcnt(0)" ::: "memory");
    else if constexpr (N == 2) asm volatile("s_waitcnt vmcnt(2)" ::: "memory");
    else if constexpr (N == 4) asm volatile("s_waitcnt vmcnt(4)" ::: "memory");
    else if constexpr (N == 6) asm volatile("s_waitcnt vmcnt(6)" ::: "memory");
    else                       asm volatile("s_waitcnt vmcnt(8)" ::: "memory");
    __builtin_amdgcn_sched_barrier(0);
}
__device__ __forceinline__ void lbar() {   // raw barrier: lgkm only, vmcnt NOT drained
    asm volatile("s_waitcnt lgkmcnt(0)" ::: "memory");
    __builtin_amdgcn_sched_barrier(0);
    __builtin_amdgcn_s_barrier();
    __builtin_amdgcn_sched_barrier(0);
}

// ---------------- D0: W transpose + f32->bf16 + deg zeroing ----------------
// (384 blocks x 256 thr covers n=50000 for the deg zeroing; folds the memset)
__global__ __launch_bounds__(256) void wcvt_kernel(const float* __restrict__ W1, const float* __restrict__ W2,
                                                   short* __restrict__ w1t, short* __restrict__ w2t,
                                                   int* __restrict__ deg, int n) {
    int t = blockIdx.x * 256 + threadIdx.x;
    if (t < n) deg[t] = 0;
    if (t < IN1 * NOUT) {
        int c = t & 127, k = t >> 7;
        w1t[c * IN1 + k] = f2bf(W1[t]);
    } else if (t < (IN1 + IN2) * NOUT) {
        int u = t - IN1 * NOUT;
        int c = u & 127, k = u >> 7;
        w2t[c * IN2 + k] = f2bf(W2[u]);
    }
}

// ---------------- gemm: B in padded LDS + asm counted ladder (R17, 93 us) ----
// Per 128-K phase and per wave: issue 4 B loads then 8 A loads (asm, explicit
// dest regs -> allocator cannot sink/serialize). Counted drains: vmcnt(8) ->
// B landed -> ds_write -> raw barrier (A stays in flight); per step j
// vmcnt(6-2j). vmcnt==0 at phase end. Bs[col][136] pad: frag reads 2-way max.
template<int K, int COLOFF>
__device__ __forceinline__ void gemm_asm(const float* __restrict__ X, const short* __restrict__ Wt,
                                         short* __restrict__ xw, unsigned short (*Bs)[136],
                                         int blk, int n) {
    constexpr int NPH = K / 128;            // 4 (mod1) or 2 (mod2)
    const int tid  = threadIdx.x;
    const int wave = tid >> 6;              // 0..7
    const int lane = tid & 63;
    const int l15 = lane & 15, kof = lane >> 4;
    int row = blk * 128 + wave * 16 + l15;
    const bool rok = (row < n);
    if (!rok) row = n - 1;
    const float* ap = X + (size_t)row * K + kof * 8;

    const int sc = tid >> 2, sq = tid & 3;
    const short* wsrc = Wt + (size_t)sc * K;

    frag_cd acc[8];
    #pragma unroll
    for (int cf = 0; cf < 8; ++cf) acc[cf] = (frag_cd){0.f, 0.f, 0.f, 0.f};

    auto cvt = [&](float4 m0, float4 m1) -> frag_ab {
        frag_ab o;
        o[0] = f2bf(m0.x); o[1] = f2bf(m0.y); o[2] = f2bf(m0.z); o[3] = f2bf(m0.w);
        o[4] = f2bf(m1.x); o[5] = f2bf(m1.y); o[6] = f2bf(m1.z); o[7] = f2bf(m1.w);
        return o;
    };
    auto compute = [&](frag_ab fa, int sl) {
        __builtin_amdgcn_s_setprio(1);
        #pragma unroll
        for (int cf = 0; cf < 8; ++cf) {
            frag_ab b = *reinterpret_cast<const frag_ab*>(&Bs[cf * 16 + l15][(sl * 4 + kof) * 8]);
            acc[cf] = __builtin_amdgcn_mfma_f32_16x16x32_bf16(b, fa, acc[cf], 0, 0, 0);
        }
        __builtin_amdgcn_s_setprio(0);
    };

    #pragma unroll
    for (int ph = 0; ph < NPH; ++ph) {
        const int kb = ph * 128;
        frag_ab b0 = gloadb(wsrc + kb + (sq * 4 + 0) * 8);
        frag_ab b1 = gloadb(wsrc + kb + (sq * 4 + 1) * 8);
        frag_ab b2 = gloadb(wsrc + kb + (sq * 4 + 2) * 8);
        frag_ab b3 = gloadb(wsrc + kb + (sq * 4 + 3) * 8);
        float4 a0 = gload(ap + kb +  0), a1 = gload(ap + kb +   4);
        float4 a2 = gload(ap + kb + 32), a3 = gload(ap + kb +  36);
        float4 a4 = gload(ap + kb + 64), a5 = gload(ap + kb +  68);
        float4 a6 = gload(ap + kb + 96), a7 = gload(ap + kb + 100);

        if (ph) lbar();                      // prev-phase readers done (A stays in flight)
        vwait<8>();                          // B landed (oldest 4 of 12)
        *reinterpret_cast<frag_ab*>(&Bs[sc][(sq * 4 + 0) * 8]) = b0;
        *reinterpret_cast<frag_ab*>(&Bs[sc][(sq * 4 + 1) * 8]) = b1;
        *reinterpret_cast<frag_ab*>(&Bs[sc][(sq * 4 + 2) * 8]) = b2;
        *reinterpret_cast<frag_ab*>(&Bs[sc][(sq * 4 + 3) * 8]) = b3;
        lbar();                              // staged B visible

        vwait<6>(); compute(cvt(a0, a1), 0);
        vwait<4>(); compute(cvt(a2, a3), 1);
        vwait<2>(); compute(cvt(a4, a5), 2);
        vwait<0>(); compute(cvt(a6, a7), 3);
    }

    if (rok) {
        short* dst = xw + (size_t)row * FTOT + COLOFF + kof * 4;
        #pragma unroll
        for (int cf = 0; cf < 8; ++cf) {
            short4v pk;
            pk[0] = f2bf(acc[cf][0]); pk[1] = f2bf(acc[cf][1]);
            pk[2] = f2bf(acc[cf][2]); pk[3] = f2bf(acc[cf][3]);
            *reinterpret_cast<short4v*>(dst + cf * 16) = pk;
        }
    }
}

// D1 mega: gemm1 || gemm2 || hist(+rank). Strict role guards (R8 lesson).
__global__ __launch_bounds__(512, 2) void mega_kernel(const float* __restrict__ x1, const short* __restrict__ w1t,
                                                      const float* __restrict__ x2, const short* __restrict__ w2t,
                                                      short* __restrict__ xw, const int* __restrict__ ei,
                                                      int* __restrict__ deg, int* __restrict__ rank,
                                                      int n, int e, int g1b, int g2b, int nhb) {
    __shared__ __align__(16) unsigned short Bs[128][136];   // 34,816 B
    int b = blockIdx.x;
    if (b < g1b) {
        gemm_asm<IN1, 0>(x1, w1t, xw, Bs, b, n);
    } else if (b < g1b + g2b) {
        gemm_asm<IN2, 128>(x2, w2t, xw, Bs, b - g1b, n);
    } else if (b < g1b + g2b + nhb) {
        for (int i = (b - g1b - g2b) * 512 + threadIdx.x; i < e; i += nhb * 512) {
            int old = atomicAdd(&deg[ei[e + i]], 1);
            rank[i] = old;
        }
    }
}

// ---------------- D2: fused single-dispatch scan ----------------
// Block bid: (a) prefix base = sum deg[0..bid*256) via strided loop (deg is
// 200 KB, L2-resident; total extra reads ~19 MB -- trivial); (b) local
// inclusive scan of its 256 deg values; (c) emit dinv + rowptr. Replaces the
// 3-dispatch scan chain.
__global__ __launch_bounds__(256) void scan_fused_kernel(const int* __restrict__ deg, float* __restrict__ dinv,
                                                         int* __restrict__ rowptr, int n) {
    __shared__ int s[256];
    const int tid = threadIdx.x, bid = blockIdx.x;
    const int base = bid * 256;
    int part = 0;
    for (int k = tid; k < base; k += 256) part += deg[k];
    s[tid] = part; __syncthreads();
    #pragma unroll
    for (int off = 128; off > 0; off >>= 1) {
        if (tid < off) s[tid] += s[tid + off];
        __syncthreads();
    }
    const int rbase = s[0];
    __syncthreads();
    int i = base + tid;
    int v = (i < n) ? deg[i] : 0;
    if (i < n) dinv[i] = rsqrtf((float)(v + 1));
    s[tid] = v; __syncthreads();
    for (int off = 1; off < 256; off <<= 1) {
        int u = (tid >= off) ? s[tid - off] : 0;
        __syncthreads();
        s[tid] += u;
        __syncthreads();
    }
    if (i < n) rowptr[i] = rbase + s[tid] - v;
    if (i == n - 1) rowptr[n] = rbase + s[tid];
}

// ---------------- D3: rank-based CSR fill (atomic-free) ----------------
__global__ __launch_bounds__(256) void fill_rank_kernel(const int* __restrict__ ei, const int* __restrict__ rowptr,
                                                        const int* __restrict__ rank, int* __restrict__ adj, int e) {
    int i = blockIdx.x * 256 + threadIdx.x;
    if (i < e) {
        int dst = ei[e + i];
        adj[rowptr[dst] + rank[i]] = ei[i];
    }
}

// ---------------- D4: gather + epilogue (unchanged) ----------------
__global__ __launch_bounds__(256) void gather_kernel(const unsigned short* __restrict__ xw,
                                                     const int* __restrict__ rowptr,
                                                     const int* __restrict__ adj,
                                                     const float* __restrict__ dinv,
                                                     const float* __restrict__ b1,
                                                     const float* __restrict__ b2,
                                                     float* __restrict__ out, int n) {
    int wid  = (int)((blockIdx.x * (size_t)blockDim.x + threadIdx.x) >> 6);
    int lane = threadIdx.x & 63;
    if (wid >= n) return;

    const ushort4* base = reinterpret_cast<const ushort4*>(xw);
    float ax = 0.f, ay = 0.f, az = 0.f, aw = 0.f;

    const int s = rowptr[wid], e = rowptr[wid + 1];
    int i = s;
    for (; i + 3 < e; i += 4) {
        int s0 = adj[i], s1 = adj[i + 1], s2 = adj[i + 2], s3 = adj[i + 3];
        float w0 = dinv[s0], w1 = dinv[s1], w2 = dinv[s2], w3 = dinv[s3];
        ushort4 v0 = base[(size_t)s0 * 64 + lane];
        ushort4 v1 = base[(size_t)s1 * 64 + lane];
        ushort4 v2 = base[(size_t)s2 * 64 + lane];
        ushort4 v3 = base[(size_t)s3 * 64 + lane];
        ax = fmaf(bf2f(v0.x), w0, fmaf(bf2f(v1.x), w1, fmaf(bf2f(v2.x), w2, fmaf(bf2f(v3.x), w3, ax))));
        ay = fmaf(bf2f(v0.y), w0, fmaf(bf2f(v1.y), w1, fmaf(bf2f(v2.y), w2, fmaf(bf2f(v3.y), w3, ay))));
        az = fmaf(bf2f(v0.z), w0, fmaf(bf2f(v1.z), w1, fmaf(bf2f(v2.z), w2, fmaf(bf2f(v3.z), w3, az))));
        aw = fmaf(bf2f(v0.w), w0, fmaf(bf2f(v1.w), w1, fmaf(bf2f(v2.w), w2, fmaf(bf2f(v3.w), w3, aw))));
    }
    for (; i < e; ++i) {
        int s0 = adj[i];
        float w0 = dinv[s0];
        ushort4 v0 = base[(size_t)s0 * 64 + lane];
        ax = fmaf(bf2f(v0.x), w0, ax); ay = fmaf(bf2f(v0.y), w0, ay);
        az = fmaf(bf2f(v0.z), w0, az); aw = fmaf(bf2f(v0.w), w0, aw);
    }
    float di = dinv[wid];
    {   // self-loop
        ushort4 v = base[(size_t)wid * 64 + lane];
        ax = fmaf(bf2f(v.x), di, ax); ay = fmaf(bf2f(v.y), di, ay);
        az = fmaf(bf2f(v.z), di, az); aw = fmaf(bf2f(v.w), di, aw);
    }
    float4 bias = (lane < 32) ? reinterpret_cast<const float4*>(b1)[lane]
                              : reinterpret_cast<const float4*>(b2)[lane - 32];
    float4 v;
    v.x = fmaxf(fmaf(ax, di, bias.x), 0.f);
    v.y = fmaxf(fmaf(ay, di, bias.y), 0.f);
    v.z = fmaxf(fmaf(az, di, bias.z), 0.f);
    v.w = fmaxf(fmaf(aw, di, bias.w), 0.f);

    float4 h;
    h.x = v.x + __shfl_xor(v.x, 32);
    h.y = v.y + __shfl_xor(v.y, 32);
    h.z = v.z + __shfl_xor(v.z, 32);
    h.w = v.w + __shfl_xor(v.w, 32);

    float m = fmaxf(fmaxf(h.x, h.y), fmaxf(h.z, h.w));
    #pragma unroll
    for (int off = 1; off <= 16; off <<= 1) m = fmaxf(m, __shfl_xor(m, off));
    float ssum = __expf(h.x - m) + __expf(h.y - m) + __expf(h.z - m) + __expf(h.w - m);
    #pragma unroll
    for (int off = 1; off <= 16; off <<= 1) ssum += __shfl_xor(ssum, off);
    float lse = m + __logf(ssum);

    if (lane < 32) {
        float4 y;
        y.x = h.x - lse; y.y = h.y - lse; y.z = h.z - lse; y.w = h.w - lse;
        reinterpret_cast<float4*>(out)[(size_t)wid * 32 + lane] = y;
    }
}

// ---------------- launcher ----------------
extern "C" void kernel_launch(void* const* d_in, const int* in_sizes, int n_in,
                              void* d_out, int out_size, void* d_ws, size_t ws_size,
                              hipStream_t stream) {
    const float* x1 = (const float*)d_in[0];
    const float* x2 = (const float*)d_in[1];
    const int*   ei = (const int*)d_in[2];
    const float* W1 = (const float*)d_in[3];
    const float* b1 = (const float*)d_in[4];
    const float* W2 = (const float*)d_in[5];
    const float* b2 = (const float*)d_in[6];
    float* out = (float*)d_out;

    const int n = in_sizes[0] / IN1;       // 50000
    const int e = in_sizes[2] / 2;         // 800000

    char* ws = (char*)d_ws;
    short* xw     = (short*)(ws + OFF_XW);
    short* w1t    = (short*)(ws + OFF_W1T);
    short* w2t    = (short*)(ws + OFF_W2T);
    int*   deg    = (int*)  (ws + OFF_DEG);
    float* dinv   = (float*)(ws + OFF_DINV);
    int*   rowptr = (int*)  (ws + OFF_ROWPTR);
    int*   adj    = (int*)  (ws + OFF_ADJ);
    int*   rank   = (int*)  (ws + OFF_RANK);

    const int nb_n = (n + 255) / 256;      // 196
    const int nb_e = (e + 255) / 256;      // 3125
    const int nwb  = ((IN1 + IN2) * NOUT + 255) / 256;   // 384 (covers deg zeroing too)
    const int g1b  = (n + 127) / 128;      // 391 gemm1 blocks (128 rows, 8 waves)
    const int g2b  = g1b;                  // 391 gemm2 blocks
    const int nhb  = 391;                  // hist blocks (grid-stride, 512 thr)

    // D0: W convert + deg zero (memset folded in)
    wcvt_kernel<<<nwb, 256, 0, stream>>>(W1, W2, w1t, w2t, deg, n);
    // D1: gemm1 || gemm2 || hist(+rank)
    mega_kernel<<<g1b + g2b + nhb, 512, 0, stream>>>(x1, w1t, x2, w2t, xw, ei, deg, rank, n, e, g1b, g2b, nhb);
    // D2: fused scan -> dinv, rowptr (one dispatch, was three)
    scan_fused_kernel<<<nb_n, 256, 0, stream>>>(deg, dinv, rowptr, n);
    // D3: rank-based CSR fill (atomic-free)
    fill_rank_kernel<<<nb_e, 256, 0, stream>>>(ei, rowptr, rank, adj, e);
    // D4: gather + relu + add + log_softmax
    const int gb = (n + 3) / 4;
    gather_kernel<<<gb, 256, 0, stream>>>((const unsigned short*)xw, rowptr, adj, dinv, b1, b2, out, n);
}

// Round 21
// 153.086 us; speedup vs baseline: 1.1212x; 1.1183x over previous
//
#include <hip/hip_runtime.h>
#include <hip/hip_bf16.h>
#include <math.h>

#define NNODES 50000
#define NEDGES 800000
#define IN1 512
#define IN2 256
#define NOUT 128
#define FTOT 256   // combined feature width (two GCN branches)

typedef __attribute__((ext_vector_type(4))) short short4v;
typedef __attribute__((ext_vector_type(8))) short frag_ab;
typedef __attribute__((ext_vector_type(4))) float frag_cd;

// ---------------- workspace layout (bytes) ----------------
#define OFF_XW      ((size_t)0)           // N*256 bf16 = 25,600,000
#define OFF_W1T     ((size_t)25600000)    // 128x512 bf16 [col][k]
#define OFF_W2T     ((size_t)25731072)    // 128x256 bf16 [col][k]
#define OFF_DEG     ((size_t)25796608)    // N int
#define OFF_DINV    ((size_t)25996672)    // N f32
#define OFF_ROWPTR  ((size_t)26196736)    // (N+1) int
#define OFF_BSUM    ((size_t)26596864)    // 256 int
#define OFF_ADJ     ((size_t)26600960)    // E int
#define OFF_RANK    ((size_t)29800960)    // E int (edge rank within dst, from hist)

__device__ __forceinline__ short f2bf(float f) {
    union { float f; unsigned u; } x; x.f = f;
    unsigned r = x.u + 0x7fffu + ((x.u >> 16) & 1u);   // RNE
    return (short)(r >> 16);
}
__device__ __forceinline__ float bf2f(unsigned short u) {
    union { unsigned u; float f; } x; x.u = ((unsigned)u) << 16;
    return x.f;
}

// ---- inline-asm vmem primitives (R17-proven: issue batch + counted ladder +
// consume in the SAME scope; no in-flight registers cross barriers (R18 NaN).
// sched_barrier after each wait per rule #18.
__device__ __forceinline__ float4 gload(const float* p) {
    float4 r;
    asm volatile("global_load_dwordx4 %0, %1, off" : "=v"(r) : "v"(p));
    return r;
}
__device__ __forceinline__ frag_ab gloadb(const short* p) {
    frag_ab r;
    asm volatile("global_load_dwordx4 %0, %1, off" : "=v"(r) : "v"(p));
    return r;
}
template<int N> __device__ __forceinline__ void vwait() {
    if constexpr (N == 0)      asm volatile("s_waitcnt vmcnt(0)" ::: "memory");
    else if constexpr (N == 2) asm volatile("s_waitcnt vmcnt(2)" ::: "memory");
    else if constexpr (N == 4) asm volatile("s_waitcnt vmcnt(4)" ::: "memory");
    else if constexpr (N == 6) asm volatile("s_waitcnt vmcnt(6)" ::: "memory");
    else                       asm volatile("s_waitcnt vmcnt(8)" ::: "memory");
    __builtin_amdgcn_sched_barrier(0);
}
__device__ __forceinline__ void lbar() {   // raw barrier: lgkm only, vmcnt NOT drained
    asm volatile("s_waitcnt lgkmcnt(0)" ::: "memory");
    __builtin_amdgcn_sched_barrier(0);
    __builtin_amdgcn_s_barrier();
    __builtin_amdgcn_sched_barrier(0);
}

// ---------------- D0: W transpose + f32->bf16 + deg zeroing ----------------
__global__ __launch_bounds__(256) void wcvt_kernel(const float* __restrict__ W1, const float* __restrict__ W2,
                                                   short* __restrict__ w1t, short* __restrict__ w2t,
                                                   int* __restrict__ deg, int n) {
    int t = blockIdx.x * 256 + threadIdx.x;
    if (t < n) deg[t] = 0;
    if (t < IN1 * NOUT) {
        int c = t & 127, k = t >> 7;
        w1t[c * IN1 + k] = f2bf(W1[t]);
    } else if (t < (IN1 + IN2) * NOUT) {
        int u = t - IN1 * NOUT;
        int c = u & 127, k = u >> 7;
        w2t[c * IN2 + k] = f2bf(W2[u]);
    }
}

// ---------------- gemm: B in padded LDS + asm counted ladder (R17, 93 us) ----
// Per 128-K phase and per wave: issue 4 B loads then 8 A loads (asm, explicit
// dest regs -> allocator cannot sink/serialize). Counted drains: vmcnt(8) ->
// B landed -> ds_write -> raw barrier (A stays in flight); per step j
// vmcnt(6-2j). vmcnt==0 at phase end. Bs[col][136] pad: frag reads 2-way max.
template<int K, int COLOFF>
__device__ __forceinline__ void gemm_asm(const float* __restrict__ X, const short* __restrict__ Wt,
                                         short* __restrict__ xw, unsigned short (*Bs)[136],
                                         int blk, int n) {
    constexpr int NPH = K / 128;            // 4 (mod1) or 2 (mod2)
    const int tid  = threadIdx.x;
    const int wave = tid >> 6;              // 0..7
    const int lane = tid & 63;
    const int l15 = lane & 15, kof = lane >> 4;
    int row = blk * 128 + wave * 16 + l15;
    const bool rok = (row < n);
    if (!rok) row = n - 1;
    const float* ap = X + (size_t)row * K + kof * 8;

    const int sc = tid >> 2, sq = tid & 3;
    const short* wsrc = Wt + (size_t)sc * K;

    frag_cd acc[8];
    #pragma unroll
    for (int cf = 0; cf < 8; ++cf) acc[cf] = (frag_cd){0.f, 0.f, 0.f, 0.f};

    auto cvt = [&](float4 m0, float4 m1) -> frag_ab {
        frag_ab o;
        o[0] = f2bf(m0.x); o[1] = f2bf(m0.y); o[2] = f2bf(m0.z); o[3] = f2bf(m0.w);
        o[4] = f2bf(m1.x); o[5] = f2bf(m1.y); o[6] = f2bf(m1.z); o[7] = f2bf(m1.w);
        return o;
    };
    auto compute = [&](frag_ab fa, int sl) {
        __builtin_amdgcn_s_setprio(1);
        #pragma unroll
        for (int cf = 0; cf < 8; ++cf) {
            frag_ab b = *reinterpret_cast<const frag_ab*>(&Bs[cf * 16 + l15][(sl * 4 + kof) * 8]);
            acc[cf] = __builtin_amdgcn_mfma_f32_16x16x32_bf16(b, fa, acc[cf], 0, 0, 0);
        }
        __builtin_amdgcn_s_setprio(0);
    };

    #pragma unroll
    for (int ph = 0; ph < NPH; ++ph) {
        const int kb = ph * 128;
        frag_ab b0 = gloadb(wsrc + kb + (sq * 4 + 0) * 8);
        frag_ab b1 = gloadb(wsrc + kb + (sq * 4 + 1) * 8);
        frag_ab b2 = gloadb(wsrc + kb + (sq * 4 + 2) * 8);
        frag_ab b3 = gloadb(wsrc + kb + (sq * 4 + 3) * 8);
        float4 a0 = gload(ap + kb +  0), a1 = gload(ap + kb +   4);
        float4 a2 = gload(ap + kb + 32), a3 = gload(ap + kb +  36);
        float4 a4 = gload(ap + kb + 64), a5 = gload(ap + kb +  68);
        float4 a6 = gload(ap + kb + 96), a7 = gload(ap + kb + 100);

        if (ph) lbar();                      // prev-phase readers done (A stays in flight)
        vwait<8>();                          // B landed (oldest 4 of 12)
        *reinterpret_cast<frag_ab*>(&Bs[sc][(sq * 4 + 0) * 8]) = b0;
        *reinterpret_cast<frag_ab*>(&Bs[sc][(sq * 4 + 1) * 8]) = b1;
        *reinterpret_cast<frag_ab*>(&Bs[sc][(sq * 4 + 2) * 8]) = b2;
        *reinterpret_cast<frag_ab*>(&Bs[sc][(sq * 4 + 3) * 8]) = b3;
        lbar();                              // staged B visible

        vwait<6>(); compute(cvt(a0, a1), 0);
        vwait<4>(); compute(cvt(a2, a3), 1);
        vwait<2>(); compute(cvt(a4, a5), 2);
        vwait<0>(); compute(cvt(a6, a7), 3);
    }

    if (rok) {
        short* dst = xw + (size_t)row * FTOT + COLOFF + kof * 4;
        #pragma unroll
        for (int cf = 0; cf < 8; ++cf) {
            short4v pk;
            pk[0] = f2bf(acc[cf][0]); pk[1] = f2bf(acc[cf][1]);
            pk[2] = f2bf(acc[cf][2]); pk[3] = f2bf(acc[cf][3]);
            *reinterpret_cast<short4v*>(dst + cf * 16) = pk;
        }
    }
}

// D1 mega: gemm1 || gemm2 || hist(+rank). Strict role guards (R8 lesson).
__global__ __launch_bounds__(512, 2) void mega_kernel(const float* __restrict__ x1, const short* __restrict__ w1t,
                                                      const float* __restrict__ x2, const short* __restrict__ w2t,
                                                      short* __restrict__ xw, const int* __restrict__ ei,
                                                      int* __restrict__ deg, int* __restrict__ rank,
                                                      int n, int e, int g1b, int g2b, int nhb) {
    __shared__ __align__(16) unsigned short Bs[128][136];   // 34,816 B
    int b = blockIdx.x;
    if (b < g1b) {
        gemm_asm<IN1, 0>(x1, w1t, xw, Bs, b, n);
    } else if (b < g1b + g2b) {
        gemm_asm<IN2, 128>(x2, w2t, xw, Bs, b - g1b, n);
    } else if (b < g1b + g2b + nhb) {
        for (int i = (b - g1b - g2b) * 512 + threadIdx.x; i < e; i += nhb * 512) {
            int old = atomicAdd(&deg[ei[e + i]], 1);
            rank[i] = old;
        }
    }
}

// ---------------- D2a: per-block deg sums + dinv ----------------
__global__ __launch_bounds__(256) void scan_part_kernel(const int* __restrict__ deg, float* __restrict__ dinv,
                                                        int* __restrict__ bsum, int n) {
    __shared__ int s[256];
    int t = threadIdx.x;
    int i = blockIdx.x * 256 + t;
    int v = (i < n) ? deg[i] : 0;
    if (i < n) dinv[i] = rsqrtf((float)(v + 1));
    s[t] = v; __syncthreads();
    #pragma unroll
    for (int off = 128; off > 0; off >>= 1) {
        if (t < off) s[t] += s[t + off];
        __syncthreads();
    }
    if (t == 0) bsum[blockIdx.x] = s[0];
}

// ---------------- D2b: rowptr (prefix over bsum -- <=196 values, O(1)) -------
// R20 lesson: the prefix MUST be over bsum (one value per thread, tree
// reduce), not over deg directly (bid*256 serial strided loads = ~16 us).
__global__ __launch_bounds__(256) void scan_write_kernel(const int* __restrict__ deg, const int* __restrict__ bsum,
                                                         int* __restrict__ rowptr, int n, int nb) {
    __shared__ int s[256];
    const int tid = threadIdx.x, bid = blockIdx.x;
    int part = (tid < bid) ? bsum[tid] : 0;      // nb <= 256: one value per thread
    s[tid] = part; __syncthreads();
    #pragma unroll
    for (int off = 128; off > 0; off >>= 1) {
        if (tid < off) s[tid] += s[tid + off];
        __syncthreads();
    }
    const int rbase = s[0];
    __syncthreads();
    int i = bid * 256 + tid;
    int v = (i < n) ? deg[i] : 0;
    s[tid] = v; __syncthreads();
    for (int off = 1; off < 256; off <<= 1) {
        int u = (tid >= off) ? s[tid - off] : 0;
        __syncthreads();
        s[tid] += u;
        __syncthreads();
    }
    if (i < n) rowptr[i] = rbase + s[tid] - v;
    if (i == n - 1) rowptr[n] = rbase + s[tid];
}

// ---------------- D3: rank-based CSR fill (atomic-free) ----------------
__global__ __launch_bounds__(256) void fill_rank_kernel(const int* __restrict__ ei, const int* __restrict__ rowptr,
                                                        const int* __restrict__ rank, int* __restrict__ adj, int e) {
    int i = blockIdx.x * 256 + threadIdx.x;
    if (i < e) {
        int dst = ei[e + i];
        adj[rowptr[dst] + rank[i]] = ei[i];
    }
}

// ---------------- D4: gather + epilogue (unchanged) ----------------
__global__ __launch_bounds__(256) void gather_kernel(const unsigned short* __restrict__ xw,
                                                     const int* __restrict__ rowptr,
                                                     const int* __restrict__ adj,
                                                     const float* __restrict__ dinv,
                                                     const float* __restrict__ b1,
                                                     const float* __restrict__ b2,
                                                     float* __restrict__ out, int n) {
    int wid  = (int)((blockIdx.x * (size_t)blockDim.x + threadIdx.x) >> 6);
    int lane = threadIdx.x & 63;
    if (wid >= n) return;

    const ushort4* base = reinterpret_cast<const ushort4*>(xw);
    float ax = 0.f, ay = 0.f, az = 0.f, aw = 0.f;

    const int s = rowptr[wid], e = rowptr[wid + 1];
    int i = s;
    for (; i + 3 < e; i += 4) {
        int s0 = adj[i], s1 = adj[i + 1], s2 = adj[i + 2], s3 = adj[i + 3];
        float w0 = dinv[s0], w1 = dinv[s1], w2 = dinv[s2], w3 = dinv[s3];
        ushort4 v0 = base[(size_t)s0 * 64 + lane];
        ushort4 v1 = base[(size_t)s1 * 64 + lane];
        ushort4 v2 = base[(size_t)s2 * 64 + lane];
        ushort4 v3 = base[(size_t)s3 * 64 + lane];
        ax = fmaf(bf2f(v0.x), w0, fmaf(bf2f(v1.x), w1, fmaf(bf2f(v2.x), w2, fmaf(bf2f(v3.x), w3, ax))));
        ay = fmaf(bf2f(v0.y), w0, fmaf(bf2f(v1.y), w1, fmaf(bf2f(v2.y), w2, fmaf(bf2f(v3.y), w3, ay))));
        az = fmaf(bf2f(v0.z), w0, fmaf(bf2f(v1.z), w1, fmaf(bf2f(v2.z), w2, fmaf(bf2f(v3.z), w3, az))));
        aw = fmaf(bf2f(v0.w), w0, fmaf(bf2f(v1.w), w1, fmaf(bf2f(v2.w), w2, fmaf(bf2f(v3.w), w3, aw))));
    }
    for (; i < e; ++i) {
        int s0 = adj[i];
        float w0 = dinv[s0];
        ushort4 v0 = base[(size_t)s0 * 64 + lane];
        ax = fmaf(bf2f(v0.x), w0, ax); ay = fmaf(bf2f(v0.y), w0, ay);
        az = fmaf(bf2f(v0.z), w0, az); aw = fmaf(bf2f(v0.w), w0, aw);
    }
    float di = dinv[wid];
    {   // self-loop
        ushort4 v = base[(size_t)wid * 64 + lane];
        ax = fmaf(bf2f(v.x), di, ax); ay = fmaf(bf2f(v.y), di, ay);
        az = fmaf(bf2f(v.z), di, az); aw = fmaf(bf2f(v.w), di, aw);
    }
    float4 bias = (lane < 32) ? reinterpret_cast<const float4*>(b1)[lane]
                              : reinterpret_cast<const float4*>(b2)[lane - 32];
    float4 v;
    v.x = fmaxf(fmaf(ax, di, bias.x), 0.f);
    v.y = fmaxf(fmaf(ay, di, bias.y), 0.f);
    v.z = fmaxf(fmaf(az, di, bias.z), 0.f);
    v.w = fmaxf(fmaf(aw, di, bias.w), 0.f);

    float4 h;
    h.x = v.x + __shfl_xor(v.x, 32);
    h.y = v.y + __shfl_xor(v.y, 32);
    h.z = v.z + __shfl_xor(v.z, 32);
    h.w = v.w + __shfl_xor(v.w, 32);

    float m = fmaxf(fmaxf(h.x, h.y), fmaxf(h.z, h.w));
    #pragma unroll
    for (int off = 1; off <= 16; off <<= 1) m = fmaxf(m, __shfl_xor(m, off));
    float ssum = __expf(h.x - m) + __expf(h.y - m) + __expf(h.z - m) + __expf(h.w - m);
    #pragma unroll
    for (int off = 1; off <= 16; off <<= 1) ssum += __shfl_xor(ssum, off);
    float lse = m + __logf(ssum);

    if (lane < 32) {
        float4 y;
        y.x = h.x - lse; y.y = h.y - lse; y.z = h.z - lse; y.w = h.w - lse;
        reinterpret_cast<float4*>(out)[(size_t)wid * 32 + lane] = y;
    }
}

// ---------------- launcher ----------------
extern "C" void kernel_launch(void* const* d_in, const int* in_sizes, int n_in,
                              void* d_out, int out_size, void* d_ws, size_t ws_size,
                              hipStream_t stream) {
    const float* x1 = (const float*)d_in[0];
    const float* x2 = (const float*)d_in[1];
    const int*   ei = (const int*)d_in[2];
    const float* W1 = (const float*)d_in[3];
    const float* b1 = (const float*)d_in[4];
    const float* W2 = (const float*)d_in[5];
    const float* b2 = (const float*)d_in[6];
    float* out = (float*)d_out;

    const int n = in_sizes[0] / IN1;       // 50000
    const int e = in_sizes[2] / 2;         // 800000

    char* ws = (char*)d_ws;
    short* xw     = (short*)(ws + OFF_XW);
    short* w1t    = (short*)(ws + OFF_W1T);
    short* w2t    = (short*)(ws + OFF_W2T);
    int*   deg    = (int*)  (ws + OFF_DEG);
    float* dinv   = (float*)(ws + OFF_DINV);
    int*   rowptr = (int*)  (ws + OFF_ROWPTR);
    int*   bsum   = (int*)  (ws + OFF_BSUM);
    int*   adj    = (int*)  (ws + OFF_ADJ);
    int*   rank   = (int*)  (ws + OFF_RANK);

    const int nb_n = (n + 255) / 256;      // 196
    const int nb_e = (e + 255) / 256;      // 3125
    const int nwb  = ((IN1 + IN2) * NOUT + 255) / 256;   // 384 (covers deg zeroing too)
    const int g1b  = (n + 127) / 128;      // 391 gemm1 blocks (128 rows, 8 waves)
    const int g2b  = g1b;                  // 391 gemm2 blocks
    const int nhb  = 391;                  // hist blocks (grid-stride, 512 thr)

    // D0: W convert + deg zero (memset folded in)
    wcvt_kernel<<<nwb, 256, 0, stream>>>(W1, W2, w1t, w2t, deg, n);
    // D1: gemm1 || gemm2 || hist(+rank)
    mega_kernel<<<g1b + g2b + nhb, 512, 0, stream>>>(x1, w1t, x2, w2t, xw, ei, deg, rank, n, e, g1b, g2b, nhb);
    // D2: scans -> dinv, bsum; then rowptr (prefix over bsum, O(1)/block)
    scan_part_kernel<<<nb_n, 256, 0, stream>>>(deg, dinv, bsum, n);
    scan_write_kernel<<<nb_n, 256, 0, stream>>>(deg, bsum, rowptr, n, nb_n);
    // D3: rank-based CSR fill (atomic-free)
    fill_rank_kernel<<<nb_e, 256, 0, stream>>>(ei, rowptr, rank, adj, e);
    // D4: gather + relu + add + log_softmax
    const int gb = (n + 3) / 4;
    gather_kernel<<<gb, 256, 0, stream>>>((const unsigned short*)xw, rowptr, adj, dinv, b1, b2, out, n);
}